// Round 6
// baseline (227.654 us; speedup 1.0000x reference)
//
#include <hip/hip_runtime.h>

// int4-dequant GEMM: y[m,n] = sum_k x[m,k] * scale[n, k/128] * (q[n,k] - 8)
// x: (512,4096) f32 | weight_packed: (11008,2048) int32 (2 nibbles in low byte) |
// scales: (11008,32) f32 | out: (512,11008) f32
//
// R13 = R12 (BM=256 BN=128 BK=64, acc[4][2], KS=4 grid 688, A direct from
// fragment-layout xw, consumer-side dequant) with the 2-barrier staging
// replaced by the T3/T4 counted-vmcnt DMA pipeline:
//  1) B raw ints staged via global_load_lds (16B) into a DOUBLE-BUFFERED
//     unpadded [2][128][32]-int LDS tile. No staging regs, no ds_write, no
//     staging VALU. Bank conflicts fixed by XOR chunk swizzle c ^= row&7
//     applied to BOTH the per-lane global source address and the ds_read
//     offset (rule #21: inverse-swizzle-source + swizzle-read).
//  2) ONE raw s_barrier per K-iter, preceded by s_waitcnt vmcnt(16): the 4
//     STAGE ops are the oldest in the queue -> retired; the 16 A-loads and
//     2 scale loads stay in flight ACROSS the barrier (never vmcnt(0) in the
//     hot loop; __syncthreads is banned there). sched_barrier(0) after each
//     barrier pins ds_reads (rule #18).
//  3) A register pipeline deepened to a FULL iter: areg[4][4]
//     consume-then-refill (slot s4 refilled for kk+1 right after its MFMAs).
// Verbatim from R12: XCD mapping, dequant math, C/D mapping
// (col=lane&31, row=(r&3)+8*(r>>2)+4*(lane>>5)), partial store, reduce_k,
// fragment-layout cvt_x.

typedef __attribute__((ext_vector_type(8)))  short short8;   // 32x32x16 A/B frag
typedef __attribute__((ext_vector_type(16))) float f32x16;   // 32x32x16 C/D frag
typedef __attribute__((ext_vector_type(4)))  float f32x4;
typedef __attribute__((ext_vector_type(4)))  int   i32x4;
typedef __attribute__((ext_vector_type(2)))  int   i32x2;

#define M_DIM 512
#define N_DIM 11008
#define K_DIM 4096
#define BM 256
#define BN 128
#define BK 64
#define KSPLIT 4
#define THREADS 256
#define NTILE_M (M_DIM / BM)        // 2
#define NTILE_N (N_DIM / BN)        // 86
#define NTILES  (NTILE_M * NTILE_N) // 172
#define TILE_ELEMS (BM * BN)        // 32768
#define KB16    (K_DIM / 16)        // 256 k-subtiles per 32-row m-stripe

typedef __attribute__((address_space(3))) unsigned int       lds_u32;
typedef const __attribute__((address_space(1))) unsigned int glb_u32;

#if defined(__has_builtin)
#  if __has_builtin(__builtin_amdgcn_cvt_pk_bf16_f32)
#    define HAVE_PK_BF16 1
#  endif
#endif
#ifndef HAVE_PK_BF16
#  define HAVE_PK_BF16 0
#endif

__device__ __forceinline__ unsigned int fbits(float f) {
    union { float f; unsigned int u; } c; c.f = f; return c.u;
}
__device__ __forceinline__ int pack2bf(float lo, float hi) {  // [hi|lo] bf16, RNE
#if HAVE_PK_BF16
    typedef __attribute__((ext_vector_type(2))) __bf16 bf16x2;
    bf16x2 p = __builtin_amdgcn_cvt_pk_bf16_f32(lo, hi);
    int r; __builtin_memcpy(&r, &p, 4);
    return r;
#else
    unsigned int ul = fbits(lo), uh = fbits(hi);
    unsigned int l = (ul + 0x7FFFu + ((ul >> 16) & 1u)) >> 16;
    unsigned int h = (uh + 0x7FFFu + ((uh >> 16) & 1u)) & 0xFFFF0000u;
    return (int)(h | l);
#endif
}

// ---- x f32 -> bf16 fragment-layout workspace (verified R10/R12) ----
// chunk c in [0, M*K/8): lane=c&63, kb16=(c>>6)&255, mb=c>>14
// m = mb*32 + (lane&31), k = kb16*16 + (lane>>5)*8
__global__ __launch_bounds__(THREADS)
void cvt_x(const float* __restrict__ x, unsigned short* __restrict__ xw)
{
    int c    = blockIdx.x * THREADS + threadIdx.x;
    int lane = c & 63;
    int kb   = (c >> 6) & (KB16 - 1);
    int mb   = c >> 14;
    int m    = mb * 32 + (lane & 31);
    int k    = kb * 16 + (lane >> 5) * 8;

    const float* src = x + (size_t)m * K_DIM + k;
    f32x4 v0 = *(const f32x4*)(src);
    f32x4 v1 = *(const f32x4*)(src + 4);
    i32x4 p;
    p[0] = pack2bf(v0[0], v0[1]);
    p[1] = pack2bf(v0[2], v0[3]);
    p[2] = pack2bf(v1[0], v1[1]);
    p[3] = pack2bf(v1[2], v1[3]);
    *(i32x4*)(xw + (size_t)c * 8) = p;
}

// ---- main GEMM: 256x128 tile, 4 waves of 128x64, 32x32x16 MFMA ----
template<int KS, bool PRECVT>
__global__ __launch_bounds__(THREADS, 2)
void dq_gemm(const unsigned short* __restrict__ xw,
             const float* __restrict__ xf,
             const int* __restrict__ wp,
             const float* __restrict__ scales,
             float* __restrict__ out,
             float* __restrict__ partials)
{
    // raw B, double-buffered, UNPADDED (global_load_lds needs linear dest):
    // 2 x 128 rows x 32 ints = 32 KB. Chunk (16B) layout XOR-swizzled:
    // LDS chunk (row, cl) holds global chunk (row, cl ^ (row&7)).
    __shared__ __align__(16) int sBr[2][BN][32];

    const int t  = threadIdx.x;
    const int bx = blockIdx.x;

    int m_idx, nb, ksp;
    if (KS == 4) {
        // verbatim R7/R12: bx and bx+8 land on the same XCD; pair the two
        // m-blocks of one (n,ksp) for weight L2 reuse.
        m_idx = (bx >> 3) & 1;
        int rest = (bx & 7) | ((bx >> 4) << 3);   // [0, 344)
        ksp = rest & 3;
        nb  = rest >> 2;
    } else {
        m_idx = bx & 1;
        nb  = bx >> 1;
        ksp = 0;
    }
    const int m0 = m_idx * BM;
    const int n0 = nb * BN;
    const int k0 = ksp * (K_DIM / KS);
    const int KITERS = (K_DIM / KS) / BK;   // 16 (KS=4) / 64 (KS=1)

    const int wave = t >> 6;
    const int lane = t & 63;
    const int wm = (wave & 1) * 128;   // 2 m-waves
    const int wn = (wave >> 1) * 64;   // 2 n-waves
    const int lr = lane & 31;          // frag row
    const int hi = lane >> 5;          // k-half selector

    // ---- B DMA staging: wave w stages chunks [w*256, w*256+256), 4 instrs.
    // chunk p: row = p>>3, cl = p&7; source chunk col = cl ^ (row&7).
    size_t srcb[4];                    // per-lane source int offset (minus w0)
    int    ldsoff[4];                  // wave-uniform LDS byte base
    {
        const int p0 = wave * 256;
        #pragma unroll
        for (int i = 0; i < 4; ++i) {
            int p = p0 + i * 64 + lane;
            int row = p >> 3, cl = p & 7;
            srcb[i] = (size_t)(n0 + row) * (K_DIM / 2) + ((cl ^ (row & 7)) << 2);
            ldsoff[i] = (p0 + i * 64) * 16;
        }
    }
    auto STAGE = [&](int kk, int buf) {
        const int w0 = (k0 + kk * BK) >> 1;          // int offset in row
        #pragma unroll
        for (int i = 0; i < 4; ++i) {
            const int* g = wp + srcb[i] + w0;
            char* l = (char*)(&sBr[0][0][0]) + buf * 16384 + ldsoff[i];
            __builtin_amdgcn_global_load_lds((glb_u32*)g, (lds_u32*)l, 16, 0, 0);
        }
    };

    // ---- A fragments: direct from fragment-layout xw (no LDS). ----
    const short8* xa8 = (const short8*)xw;
    const int mb0 = (m0 + wm) >> 5;
    size_t arow[4];
    #pragma unroll
    for (int i = 0; i < 4; ++i)
        arow[i] = (size_t)(mb0 + i) * KB16 * 64 + lane;

    auto LOADA_STEP = [&](int kk, int s4, short8 (&dst)[4]) {
        if constexpr (PRECVT) {
            const size_t kadd = (size_t)(((k0 + kk * BK) >> 4) + s4) * 64;
            #pragma unroll
            for (int i = 0; i < 4; ++i)
                dst[i] = xa8[arow[i] + kadd];
        } else {
            #pragma unroll
            for (int i = 0; i < 4; ++i) {
                const float* src = xf + (size_t)(m0 + wm + i * 32 + lr) * K_DIM
                                      + k0 + kk * BK + s4 * 16 + hi * 8;
                f32x4 v0 = *(const f32x4*)(src);
                f32x4 v1 = *(const f32x4*)(src + 4);
                i32x4 p;
                p[0] = pack2bf(v0[0], v0[1]);
                p[1] = pack2bf(v0[2], v0[3]);
                p[2] = pack2bf(v1[0], v1[1]);
                p[3] = pack2bf(v1[2], v1[3]);
                __builtin_memcpy(&dst[i], &p, 16);
            }
        }
    };

    f32x16 acc[4][2] = {};

    // consumer-side B dequant (R12's exact math), swizzled chunk read.
    auto BFRAG = [&](int buf, int s4, int j, float s, float ns8) -> short8 {
        const int row = wn + j * 32 + lr;
        const int cl  = ((s4 << 1) | hi) ^ (lr & 7);   // row&7 == lr&7 here
        const i32x4 braw = *(const i32x4*)((const char*)(&sBr[0][0][0])
                              + buf * 16384 + row * 128 + (cl << 4));
        i32x4 rr;
        #pragma unroll
        for (int e = 0; e < 4; ++e) {
            int b = braw[e];
            rr[e] = pack2bf((float)(b & 15) * s + ns8,
                            (float)((b >> 4) & 15) * s + ns8);
        }
        short8 bf; __builtin_memcpy(&bf, &rr, 16);
        return bf;
    };

    // scale rows for this wave's two n-frags
    const size_t srow0 = (size_t)(n0 + wn + lr)      * (K_DIM / 128);
    const size_t srow1 = (size_t)(n0 + wn + 32 + lr) * (K_DIM / 128);

    short8 areg[4][4];

    // ---- prologue: STAGE tile0, scales, full-iter A; counted wait ----
    STAGE(0, 0);
    float sc0 = scales[srow0 + (k0 >> 7)];
    float sc1 = scales[srow1 + (k0 >> 7)];
    #pragma unroll
    for (int s4 = 0; s4 < 4; ++s4)
        LOADA_STEP(0, s4, areg[s4]);
    asm volatile("s_waitcnt vmcnt(16)" ::: "memory");
    __builtin_amdgcn_s_barrier();
    __builtin_amdgcn_sched_barrier(0);

    // ---- steady state: ONE raw barrier per K-iter, vmcnt never 0 ----
    #pragma unroll 2
    for (int kk = 0; kk < KITERS; ++kk) {
        const int cur = kk & 1;
        if (kk + 1 < KITERS)
            STAGE(kk + 1, cur ^ 1);   // oldest in queue at the next waitcnt
        float nx0 = sc0, nx1 = sc1;
        if (kk + 1 < KITERS) {
            const int gq = (k0 + (kk + 1) * BK) >> 7;
            nx0 = scales[srow0 + gq];
            nx1 = scales[srow1 + gq];
        }
        const float s0 = sc0, n80 = sc0 * -8.0f;
        const float s1 = sc1, n81 = sc1 * -8.0f;

        #pragma unroll
        for (int s4 = 0; s4 < 4; ++s4) {
            short8 b0 = BFRAG(cur, s4, 0, s0, n80);
            short8 b1 = BFRAG(cur, s4, 1, s1, n81);
            #pragma unroll
            for (int i = 0; i < 4; ++i) {
                acc[i][0] = __builtin_amdgcn_mfma_f32_32x32x16_bf16(
                    areg[s4][i], b0, acc[i][0], 0, 0, 0);
                acc[i][1] = __builtin_amdgcn_mfma_f32_32x32x16_bf16(
                    areg[s4][i], b1, acc[i][1], 0, 0, 0);
            }
            if (kk + 1 < KITERS)                 // consume-then-refill, static idx
                LOADA_STEP(kk + 1, s4, areg[s4]);
        }
        sc0 = nx0; sc1 = nx1;

        if (kk + 1 < KITERS) {
            // queue: [STAGE(kk+1) x4 (oldest), SC x2, A-refill x16] = 22.
            // vmcnt(16) retires STAGE+SC, keeps all 16 A-loads in flight.
            asm volatile("s_waitcnt vmcnt(16)" ::: "memory");
            __builtin_amdgcn_s_barrier();
            __builtin_amdgcn_sched_barrier(0);
        }
    }

    const int rbase = hi * 4;
    if constexpr (KS == 1) {
        // direct store: C/D col=lane&31, row=(r&3)+8*(r>>2)+4*(lane>>5)
        #pragma unroll
        for (int i = 0; i < 4; ++i) {
            int mg0 = m0 + wm + i * 32 + rbase;
            #pragma unroll
            for (int j = 0; j < 2; ++j) {
                int ng = n0 + wn + j * 32 + lr;
                #pragma unroll
                for (int r = 0; r < 16; ++r)
                    out[(size_t)(mg0 + (r & 3) + 8 * (r >> 2)) * N_DIM + ng] = acc[i][j][r];
            }
        }
    } else {
        // verbatim R7/R12 lane-coalesced partial store.
        float* my = partials + ((size_t)(m_idx * NTILE_N + nb) * KS + ksp) * TILE_ELEMS;
        #pragma unroll
        for (int i = 0; i < 4; ++i)
            #pragma unroll
            for (int j = 0; j < 2; ++j)
                #pragma unroll
                for (int q = 0; q < 4; ++q) {
                    int c = (i * 2 + j) * 4 + q;
                    f32x4 v;
                    v[0] = acc[i][j][q * 4 + 0];
                    v[1] = acc[i][j][q * 4 + 1];
                    v[2] = acc[i][j][q * 4 + 2];
                    v[3] = acc[i][j][q * 4 + 3];
                    *(f32x4*)(my + c * 1024 + t * 4) = v;
                }
    }
}

// ---- reduce: verbatim R7/R12. sum 4 partials, frag-slot -> row-major ----
__global__ __launch_bounds__(THREADS)
void reduce_k(const float* __restrict__ partials, float* __restrict__ out)
{
    __shared__ float sT[128][132];   // stride 132: 16B-aligned rows, banks ok

    const int b    = blockIdx.x;
    const int tile = b >> 1;
    const int h    = b & 1;                       // m-half within the 256-row tile
    const int m_idx = tile / NTILE_N;
    const int nb    = tile % NTILE_N;
    const int m0 = m_idx * BM + h * 128;
    const int n0 = nb * BN;
    const int u  = threadIdx.x;

    const float* base = partials + (size_t)tile * KSPLIT * TILE_ELEMS;

    #pragma unroll
    for (int it = 0; it < 16; ++it) {
        int idx = it * 256 + u;                   // [0, 4096) f32x4-chunks
        int c   = idx >> 7;                       // [0,32)
        int tl  = idx & 127;
        int t   = (tl & 63) | (h << 6) | ((tl & 64) << 1);  // threads with wave&1==h
        int off = c * 1024 + t * 4;
        f32x4 s = *(const f32x4*)(base + off);
        s += *(const f32x4*)(base + TILE_ELEMS + off);
        s += *(const f32x4*)(base + 2 * TILE_ELEMS + off);
        s += *(const f32x4*)(base + 3 * TILE_ELEMS + off);
        int i = c >> 3, j = (c >> 2) & 1, q = c & 3;
        int lane = t & 63, wave = t >> 6;
        int mrow = i * 32 + (lane >> 5) * 4 + 8 * q;        // [0,128) within half
        int ncol = (wave >> 1) * 64 + j * 32 + (lane & 31);
        sT[mrow + 0][ncol] = s[0];
        sT[mrow + 1][ncol] = s[1];
        sT[mrow + 2][ncol] = s[2];
        sT[mrow + 3][ncol] = s[3];
    }
    __syncthreads();

    #pragma unroll
    for (int it = 0; it < 16; ++it) {
        int idx = it * 256 + u;                   // [0, 4096)
        int row = idx >> 5;                       // 32 f32x4 per 128-col row
        int c4  = (idx & 31) * 4;
        f32x4 v = *(const f32x4*)&sT[row][c4];
        *(f32x4*)(out + (size_t)(m0 + row) * N_DIM + n0 + c4) = v;
    }
}

extern "C" void kernel_launch(void* const* d_in, const int* in_sizes, int n_in,
                              void* d_out, int out_size, void* d_ws, size_t ws_size,
                              hipStream_t stream) {
    (void)in_sizes; (void)n_in; (void)out_size;
    const float* x      = (const float*)d_in[0];
    const int*   wpck   = (const int*)d_in[1];
    const float* scales = (const float*)d_in[2];
    float*       out    = (float*)d_out;

    const size_t XW_BYTES   = (size_t)M_DIM * K_DIM * 2;                        // 4 MB
    const size_t PART_OFF   = XW_BYTES;
    const size_t PART_BYTES = (size_t)NTILES * KSPLIT * TILE_ELEMS * 4;         // 90.2 MB

    if (ws_size >= PART_OFF + PART_BYTES) {
        unsigned short* xw  = (unsigned short*)d_ws;
        float* part = (float*)((char*)d_ws + PART_OFF);
        cvt_x<<<(M_DIM * K_DIM) / (THREADS * 8), THREADS, 0, stream>>>(x, xw);
        dq_gemm<KSPLIT, true><<<NTILES * KSPLIT, THREADS, 0, stream>>>(
            xw, x, wpck, scales, out, part);
        reduce_k<<<NTILES * 2, THREADS, 0, stream>>>(part, out);
    } else if (ws_size >= XW_BYTES) {
        unsigned short* xw = (unsigned short*)d_ws;
        cvt_x<<<(M_DIM * K_DIM) / (THREADS * 8), THREADS, 0, stream>>>(x, xw);
        dq_gemm<1, true><<<NTILES, THREADS, 0, stream>>>(
            xw, x, wpck, scales, out, nullptr);
    } else {
        dq_gemm<1, false><<<NTILES, THREADS, 0, stream>>>(
            nullptr, x, wpck, scales, out, nullptr);
    }
}